// Round 5
// baseline (470.675 us; speedup 1.0000x reference)
//
#include <hip/hip_runtime.h>

// Involution via bf16 MFMA tap-GEMM, operand-swapped (D[t][px]).
// R5: break per-iter serial chain in invol_main:
//   - all 4 x-tiles staged up front (no in-loop WAR on x_s)
//   - hb (B-frags) hoisted out of iter loop (loop-invariant)
//   - mean via u-row trick: colsum(kw) in tap rows 49/50 (bf16 hi+lo),
//     bias-sum in kbp[g][49] -> mean from MFMA output, ss = ssq - 49*m^2.

#define C_    256
#define HID_  64
#define KS_   7
#define KK_   49
#define G_    256
#define H_    64
#define W_    64
#define HW_   4096
#define BN_EPS 1e-5f

typedef __attribute__((ext_vector_type(8))) short bf16x8;
typedef __attribute__((ext_vector_type(4))) float f32x4;

__device__ __forceinline__ ushort f2bf(float f) {
    unsigned u = __float_as_uint(f);
    return (ushort)((u + 0x7fffu + ((u >> 16) & 1u)) >> 16);   // RNE
}
__device__ __forceinline__ float bf2f(ushort s) {
    return __uint_as_float((unsigned)s << 16);
}

// ---------------------------------------------------------------- prep ----
// blocks 0..255:  kwb[g][t][k] bf16 (t<49 data, 51..63 zero; skip t=49,50)
// block 256:      rwT[k][o] = reduce_w[o][k]*bn_inv[o]; betp[o]
// block 257:      kbp[g][t] = bias (t<49), bias-sum (t=49), else 0
// blocks 258+g:   kwb[g][49][k] = bf16_hi(colsum kw), kwb[g][50][k] = bf16_lo
__global__ __launch_bounds__(256) void prep_kernel(
    const float* __restrict__ kw, const float* __restrict__ kb,
    const float* __restrict__ reduce_w,
    const float* __restrict__ bn_gamma, const float* __restrict__ bn_beta,
    const float* __restrict__ bn_mean, const float* __restrict__ bn_var,
    ushort* __restrict__ kwb, float* __restrict__ rwT, float* __restrict__ betp,
    float* __restrict__ kbp)
{
    const int bid = blockIdx.x;
    if (bid < 256) {
        int idx  = bid * 256 + threadIdx.x;
        int base = idx * 16;
        int g    = base >> 12;
        int rem  = base & 4095;
        int t    = rem >> 6;
        int k0   = rem & 63;
        if (t == 49 || t == 50) return;      // owned by u-row blocks
        union { ushort s[16]; uint4 v[2]; } u;
        if (t < KK_) {
            const float* src = kw + ((size_t)(g * KK_ + t)) * HID_ + k0;
            #pragma unroll
            for (int i = 0; i < 16; ++i) u.s[i] = f2bf(src[i]);
        } else {
            #pragma unroll
            for (int i = 0; i < 16; ++i) u.s[i] = 0;
        }
        uint4* dst = (uint4*)(kwb + base);
        dst[0] = u.v[0];
        dst[1] = u.v[1];
    } else if (bid == 256) {
        int k = threadIdx.x;
        #pragma unroll 1
        for (int o = 0; o < HID_; ++o) {
            float inv = bn_gamma[o] * rsqrtf(bn_var[o] + BN_EPS);
            rwT[k * HID_ + o] = reduce_w[o * C_ + k] * inv;
        }
        if (k < HID_) {
            float inv = bn_gamma[k] * rsqrtf(bn_var[k] + BN_EPS);
            betp[k] = bn_beta[k] - bn_mean[k] * inv;
        }
    } else if (bid == 257) {
        for (int i = threadIdx.x; i < G_ * 64; i += 256) {
            int g = i >> 6, t = i & 63;
            float v = 0.f;
            if (t < KK_) {
                v = kb[g * KK_ + t];
            } else if (t == 49) {
                float s = 0.f;
                #pragma unroll 1
                for (int tt = 0; tt < KK_; ++tt) s += kb[g * KK_ + tt];
                v = s;
            }
            kbp[i] = v;
        }
    } else {
        const int g = bid - 258;
        __shared__ float part[4][64];
        const int k  = threadIdx.x & 63;
        const int pr = threadIdx.x >> 6;
        const int t0 = pr * 13;
        const int t1 = (t0 + 13 < KK_) ? t0 + 13 : KK_;
        float s = 0.f;
        for (int t = t0; t < t1; ++t)
            s += kw[((size_t)(g * KK_ + t)) * HID_ + k];
        part[pr][k] = s;
        __syncthreads();
        if (threadIdx.x < 64) {
            float u = part[0][k] + part[1][k] + part[2][k] + part[3][k];
            ushort uh = f2bf(u);
            ushort ul = f2bf(u - bf2f(uh));
            kwb[(size_t)g * 4096 + 49 * 64 + k] = uh;
            kwb[(size_t)g * 4096 + 50 * 64 + k] = ul;
        }
    }
}

// ----------------------------------------------------------------- hv1 ----
__global__ __launch_bounds__(256) void hv1_kernel(
    const float* __restrict__ x, const float* __restrict__ rwT,
    float* __restrict__ hvp, int npx)
{
    const int lane = threadIdx.x & 63;
    const int wq   = __builtin_amdgcn_readfirstlane(threadIdx.x >> 6);
    const int kq   = blockIdx.y;
    const int p    = blockIdx.x * 64 + lane;
    const int b    = p >> 12;
    const int hw   = p & 4095;

    float acc[16];
    #pragma unroll
    for (int j = 0; j < 16; ++j) acc[j] = 0.f;

    const float* xp = x + ((size_t)b * C_ + kq * 64) * HW_ + hw;
    const float* rw = rwT + (kq * 64) * HID_ + wq * 16;
    #pragma unroll 8
    for (int kk = 0; kk < 64; ++kk) {
        float xk = xp[(size_t)kk * HW_];
        #pragma unroll
        for (int j = 0; j < 16; ++j) acc[j] = fmaf(xk, rw[kk * HID_ + j], acc[j]);
    }
    float* dst = hvp + ((size_t)(kq * 64 + wq * 16)) * npx + p;
    #pragma unroll
    for (int j = 0; j < 16; ++j) dst[(size_t)j * npx] = acc[j];
}

// ----------------------------------------------------------------- hv2 ----
__global__ __launch_bounds__(256) void hv2_kernel(
    const float* __restrict__ hvp, const float* __restrict__ betp,
    ushort* __restrict__ hv, int npx)
{
    const int p  = blockIdx.x * 256 + threadIdx.x;
    const int o0 = blockIdx.y * 4;
    ushort s[4];
    #pragma unroll
    for (int j = 0; j < 4; ++j) {
        float v = 0.f;
        #pragma unroll
        for (int kq = 0; kq < 4; ++kq)
            v += hvp[(size_t)(kq * 64 + o0 + j) * npx + p];
        s[j] = f2bf(fmaxf(v + betp[o0 + j], 0.f));
    }
    uint2 w;
    w.x = (uint)s[0] | ((uint)s[1] << 16);
    w.y = (uint)s[2] | ((uint)s[3] << 16);
    *(uint2*)(hv + (size_t)p * HID_ + o0) = w;
}

// ---------------------------------------------------------------- main ----
__global__ __launch_bounds__(256) void invol_main(
    const float* __restrict__ x, const ushort* __restrict__ hv,
    const ushort* __restrict__ kwb, const float* __restrict__ kbp,
    float* __restrict__ out)
{
    __shared__ ushort hv_s[64 * HID_];         // 8 KB, XOR-swizzled rows
    __shared__ float  x_s[4][4][KS_][72];      // 32256 B: [wave][iter][row][col]

    const int tid  = threadIdx.x;
    const int lane = tid & 63;
    const int wave = __builtin_amdgcn_readfirstlane(tid >> 6);
    const int b  = blockIdx.x >> 6;
    const int y  = blockIdx.x & 63;
    const int gy = blockIdx.y;
    const int rowpix = (b << 12) + (y << 6);

    {   // stage hv row tile (swizzled: byte ^= (row&7)<<4)
        int px = tid >> 2, c = tid & 3;
        const uint4* src = (const uint4*)(hv + (size_t)(rowpix + px) * HID_ + c * 16);
        int d0 = (px * 128 + c * 32) ^ ((px & 7) << 4);
        int d1 = (px * 128 + c * 32 + 16) ^ ((px & 7) << 4);
        *(uint4*)((char*)hv_s + d0) = src[0];
        *(uint4*)((char*)hv_s + d1) = src[1];
    }

    // stage ALL 4 x-tiles for this wave's 4 groups (wave-private; loads all
    // issue up front and hide under the hv barrier + hb loads + first MFMA)
    const int  c0  = lane - 3;
    const int  c0c = c0 < 0 ? 0 : c0;
    const bool c0v = c0 >= 0;
    const int  c1  = 61 + lane;
    const int  c1c = c1 > 63 ? 63 : c1;
    const bool c1v = c1 <= 63;
    #pragma unroll
    for (int it = 0; it < 4; ++it) {
        const int g = gy * 16 + it * 4 + wave;
        const float* xg = x + ((size_t)(b * G_ + g)) * HW_;
        #pragma unroll
        for (int i = 0; i < KS_; ++i) {
            int yy = y + i - 3;
            bool rv = (unsigned)yy < (unsigned)H_;
            int yc = rv ? yy : 0;
            float v0 = xg[yc * W_ + c0c];
            x_s[wave][it][i][lane] = (rv && c0v) ? v0 : 0.f;
            if (lane < 6) {
                float v1 = xg[yc * W_ + c1c];
                x_s[wave][it][i][64 + lane] = (rv && c1v) ? v1 : 0.f;
            }
        }
    }
    __syncthreads();

    const int l15 = lane & 15;
    const int l4  = lane >> 4;

    // B frags (hv): loop-invariant across iters -> hoisted
    bf16x8 hb[2][4];
    #pragma unroll
    for (int ks = 0; ks < 2; ++ks)
        #pragma unroll
        for (int pn = 0; pn < 4; ++pn) {
            int row  = pn * 16 + l15;
            int byte = (row * 128 + ks * 64 + l4 * 16) ^ ((row & 7) << 4);
            hb[ks][pn] = *(const bf16x8*)((const char*)hv_s + byte);
        }

    // per-lane tap offsets into x_s row-space: t = tm*16 + l4*4 + r  (t<48)
    int offs[3][4];
    #pragma unroll
    for (int tm = 0; tm < 3; ++tm)
        #pragma unroll
        for (int r = 0; r < 4; ++r) {
            int t = tm * 16 + l4 * 4 + r;
            int i = (t * 147) >> 10;       // t/7 for t<64
            int j = t - i * 7;
            offs[tm][r] = i * 72 + j;
        }

    #pragma unroll
    for (int iter = 0; iter < 4; ++iter) {
        const int g = gy * 16 + iter * 4 + wave;

        // A frags (kw): rows t=tm*16+l15 (incl. u-rows 49,50)
        bf16x8 ka[2][4];
        const char* kwg = (const char*)kwb + (size_t)g * 8192;
        #pragma unroll
        for (int ks = 0; ks < 2; ++ks)
            #pragma unroll
            for (int tm = 0; tm < 4; ++tm) {
                int byte = (tm * 16 + l15) * 128 + ks * 64 + l4 * 16;
                ka[ks][tm] = *(const bf16x8*)(kwg + byte);
            }
        // bias rows for this lane (r dim): kbp[g][tm*16 + l4*4 .. +3]
        f32x4 kv[4];
        #pragma unroll
        for (int tm = 0; tm < 4; ++tm)
            kv[tm] = *(const f32x4*)(kbp + g * 64 + tm * 16 + l4 * 4);

        f32x4 acc[4][4];
        #pragma unroll
        for (int tm = 0; tm < 4; ++tm)
            #pragma unroll
            for (int pn = 0; pn < 4; ++pn) acc[tm][pn] = (f32x4)(0.f);
        #pragma unroll
        for (int ks = 0; ks < 2; ++ks)
            #pragma unroll
            for (int tm = 0; tm < 4; ++tm)
                #pragma unroll
                for (int pn = 0; pn < 4; ++pn)
                    acc[tm][pn] = __builtin_amdgcn_mfma_f32_16x16x32_bf16(
                        ka[ks][tm], hb[ks][pn], acc[tm][pn], 0, 0, 0);

        #pragma unroll
        for (int tm = 0; tm < 4; ++tm)
            #pragma unroll
            for (int pn = 0; pn < 4; ++pn)
                #pragma unroll
                for (int r = 0; r < 4; ++r) acc[tm][pn][r] += kv[tm][r];

        // norm: ssq over 49 taps; mean from u-rows (t=49 hi + t=50 lo + bsum)
        float m_all[4], inv_[4];
        #pragma unroll
        for (int pn = 0; pn < 4; ++pn) {
            float ssq = 0.f;
            #pragma unroll
            for (int tm = 0; tm < 3; ++tm)
                #pragma unroll
                for (int r = 0; r < 4; ++r) {
                    float e = acc[tm][pn][r];
                    ssq = fmaf(e, e, ssq);
                }
            float e48 = acc[3][pn][0];
            ssq += (l4 == 0) ? e48 * e48 : 0.f;
            ssq += __shfl_xor(ssq, 16);
            ssq += __shfl_xor(ssq, 32);
            // rows t=49 (r=1, has +bsum) and t=50 (r=2) live on l4==0 lanes
            float mr = acc[3][pn][1] + acc[3][pn][2];
            float m  = __shfl(mr, l15) * (1.f / 49.f);
            float ss = fmaxf(ssq - 49.f * m * m, 0.f);
            m_all[pn] = m;
            inv_[pn]  = 1.f / fmaxf(sqrtf(ss), 1e-6f);
        }

        // involution: out = (sum ker*x - mean*sum x) * inv
        float kx[4] = {0.f, 0.f, 0.f, 0.f};
        float xs[4] = {0.f, 0.f, 0.f, 0.f};
        const float* xw = &x_s[wave][iter][0][0];
        #pragma unroll
        for (int tm = 0; tm < 3; ++tm)
            #pragma unroll
            for (int r = 0; r < 4; ++r) {
                const float* base = xw + offs[tm][r] + l15;
                #pragma unroll
                for (int pn = 0; pn < 4; ++pn) {
                    float xv = base[pn * 16];
                    kx[pn] = fmaf(acc[tm][pn][r], xv, kx[pn]);
                    xs[pn] += xv;
                }
            }
        {   // t = 48 (i=6, j=6): valid only on l4==0 lanes
            const float* base = xw + 6 * 72 + 6 + l15;
            #pragma unroll
            for (int pn = 0; pn < 4; ++pn) {
                float xv = base[pn * 16];
                float kr = (l4 == 0) ? acc[3][pn][0] : 0.f;
                kx[pn] = fmaf(kr, xv, kx[pn]);
                xs[pn] += (l4 == 0) ? xv : 0.f;
            }
        }
        float ov[4];
        #pragma unroll
        for (int pn = 0; pn < 4; ++pn) {
            float k2 = kx[pn];
            k2 += __shfl_xor(k2, 16);
            k2 += __shfl_xor(k2, 32);
            float x2 = xs[pn];
            x2 += __shfl_xor(x2, 16);
            x2 += __shfl_xor(x2, 32);
            ov[pn] = (k2 - m_all[pn] * x2) * inv_[pn];
        }
        float outv = (l4 == 0) ? ov[0] : (l4 == 1) ? ov[1] : (l4 == 2) ? ov[2] : ov[3];
        out[((size_t)(b * G_ + g)) * HW_ + y * W_ + lane] = outv;
    }
}

// --------------------------------------------- tier-2 hv (single-stage) ----
__global__ __launch_bounds__(256) void hv_kernel(
    const float* __restrict__ x, const float* __restrict__ rwT,
    const float* __restrict__ betp, ushort* __restrict__ hv)
{
    const int lane = threadIdx.x & 63;
    const int q    = __builtin_amdgcn_readfirstlane(threadIdx.x >> 6);
    const int p    = blockIdx.x * 64 + lane;
    const int b    = p >> 12;
    const int hw   = p & 4095;
    float acc[16];
    #pragma unroll
    for (int j = 0; j < 16; ++j) acc[j] = betp[q * 16 + j];
    const float* xp = x + (size_t)b * C_ * HW_ + hw;
    #pragma unroll 8
    for (int k = 0; k < C_; ++k) {
        float xk = xp[(size_t)k * HW_];
        const float* rw = rwT + k * HID_ + q * 16;
        #pragma unroll
        for (int j = 0; j < 16; ++j) acc[j] = fmaf(xk, rw[j], acc[j]);
    }
    union { ushort s[16]; uint4 v[2]; } u;
    #pragma unroll
    for (int j = 0; j < 16; ++j) u.s[j] = f2bf(fmaxf(acc[j], 0.f));
    uint4* dst = (uint4*)(hv + (size_t)p * HID_ + q * 16);
    dst[0] = u.v[0];
    dst[1] = u.v[1];
}

// ---------------------------------------------------- fallback (no ws) ----
__global__ __launch_bounds__(256) void invol_fallback(
    const float* __restrict__ x, const float* __restrict__ reduce_w,
    const float* __restrict__ bn_gamma, const float* __restrict__ bn_beta,
    const float* __restrict__ bn_mean, const float* __restrict__ bn_var,
    const float* __restrict__ kw, const float* __restrict__ kb,
    float* __restrict__ out)
{
    __shared__ float rwT[C_][HID_ + 4];
    __shared__ float bns[HID_];
    __shared__ float bnb[HID_];
    const int tid = threadIdx.x;
    const int b  = blockIdx.z;
    const int g0 = blockIdx.y * 32;
    const int p  = blockIdx.x * 256 + tid;
    const int py = p >> 6;
    const int px = p & 63;
    #pragma unroll 1
    for (int o = 0; o < HID_; ++o) rwT[tid][o] = reduce_w[o * C_ + tid];
    if (tid < HID_) {
        float inv = bn_gamma[tid] * rsqrtf(bn_var[tid] + BN_EPS);
        bns[tid] = inv;
        bnb[tid] = bn_beta[tid] - bn_mean[tid] * inv;
    }
    __syncthreads();
    float hvv[HID_];
    #pragma unroll
    for (int o = 0; o < HID_; ++o) hvv[o] = 0.f;
    const float* xb = x + (size_t)b * C_ * HW_ + p;
    #pragma unroll 4
    for (int k = 0; k < C_; ++k) {
        float xk = xb[(size_t)k * HW_];
        const float4* wr = (const float4*)&rwT[k][0];
        #pragma unroll
        for (int o4 = 0; o4 < HID_ / 4; ++o4) {
            float4 w = wr[o4];
            hvv[o4*4+0] = fmaf(xk, w.x, hvv[o4*4+0]);
            hvv[o4*4+1] = fmaf(xk, w.y, hvv[o4*4+1]);
            hvv[o4*4+2] = fmaf(xk, w.z, hvv[o4*4+2]);
            hvv[o4*4+3] = fmaf(xk, w.w, hvv[o4*4+3]);
        }
    }
    #pragma unroll
    for (int o = 0; o < HID_; ++o) hvv[o] = fmaxf(fmaf(hvv[o], bns[o], bnb[o]), 0.f);
    #pragma unroll 1
    for (int gi = 0; gi < 32; ++gi) {
        const int g = g0 + gi;
        const float* kwg = kw + (size_t)g * KK_ * HID_;
        float acc[KK_];
        #pragma unroll
        for (int t = 0; t < KK_; ++t) {
            float a = kb[g * KK_ + t];
            const float4* row = (const float4*)(kwg + t * HID_);
            #pragma unroll
            for (int k4 = 0; k4 < HID_ / 4; ++k4) {
                float4 w = row[k4];
                a = fmaf(w.x, hvv[k4*4+0], a);
                a = fmaf(w.y, hvv[k4*4+1], a);
                a = fmaf(w.z, hvv[k4*4+2], a);
                a = fmaf(w.w, hvv[k4*4+3], a);
            }
            acc[t] = a;
        }
        float mean = 0.f;
        #pragma unroll
        for (int t = 0; t < KK_; ++t) mean += acc[t];
        mean *= (1.f / 49.f);
        float ss = 0.f;
        #pragma unroll
        for (int t = 0; t < KK_; ++t) { acc[t] -= mean; ss = fmaf(acc[t], acc[t], ss); }
        float inv = 1.f / fmaxf(sqrtf(ss), 1e-6f);
        const float* xg = x + ((size_t)(b * G_ + g)) * HW_;
        float oacc = 0.f;
        #pragma unroll
        for (int i = 0; i < KS_; ++i) {
            int yv = py + i - 3;
            bool rok = ((unsigned)yv < (unsigned)H_);
            const float* xrow = xg + yv * W_;
            #pragma unroll
            for (int j = 0; j < KS_; ++j) {
                int xx = px + j - 3;
                bool ok = rok && ((unsigned)xx < (unsigned)W_);
                float v = ok ? xrow[xx] : 0.f;
                oacc = fmaf(v, acc[i*7+j], oacc);
            }
        }
        out[((size_t)(b * G_ + g)) * HW_ + p] = oacc * inv;
    }
}

extern "C" void kernel_launch(void* const* d_in, const int* in_sizes, int n_in,
                              void* d_out, int out_size, void* d_ws, size_t ws_size,
                              hipStream_t stream) {
    const float* x        = (const float*)d_in[0];
    const float* reduce_w = (const float*)d_in[1];
    const float* bn_gamma = (const float*)d_in[2];
    const float* bn_beta  = (const float*)d_in[3];
    const float* bn_mean  = (const float*)d_in[4];
    const float* bn_var   = (const float*)d_in[5];
    const float* kproj_w  = (const float*)d_in[6];
    const float* kproj_b  = (const float*)d_in[7];
    float* out = (float*)d_out;
    const int B   = in_sizes[0] / (C_ * HW_);
    const int npx = B * HW_;

    size_t kwb_off = 0;
    size_t kwb_sz  = (size_t)G_ * 64 * 64 * 2;        // 2 MB
    size_t kbp_off = kwb_off + kwb_sz;
    size_t kbp_sz  = (size_t)G_ * 64 * 4;             // 64 KB
    size_t rwt_off = kbp_off + kbp_sz;
    size_t rwt_sz  = (size_t)C_ * HID_ * 4;           // 64 KB
    size_t bet_off = rwt_off + rwt_sz;
    size_t bet_sz  = 256;
    size_t hv_off  = bet_off + bet_sz;
    size_t hv_sz   = (size_t)npx * HID_ * 2;          // 2 MB
    size_t hvp_off = hv_off + hv_sz;
    size_t hvp_sz  = (size_t)4 * HID_ * npx * 4;      // 16 MB
    size_t need2   = hvp_off;                          // without hvp
    size_t need    = hvp_off + hvp_sz;

    if (ws_size < need2) {
        dim3 grid(HW_ / 256, G_ / 32, B);
        invol_fallback<<<grid, 256, 0, stream>>>(x, reduce_w, bn_gamma, bn_beta,
                                                 bn_mean, bn_var, kproj_w, kproj_b, out);
        return;
    }

    ushort* kwb  = (ushort*)((char*)d_ws + kwb_off);
    float*  kbp  = (float*)((char*)d_ws + kbp_off);
    float*  rwT  = (float*)((char*)d_ws + rwt_off);
    float*  betp = (float*)((char*)d_ws + bet_off);
    ushort* hv   = (ushort*)((char*)d_ws + hv_off);
    float*  hvp  = (float*)((char*)d_ws + hvp_off);

    prep_kernel<<<dim3(258 + G_), 256, 0, stream>>>(kproj_w, kproj_b, reduce_w,
                                                    bn_gamma, bn_beta, bn_mean, bn_var,
                                                    kwb, rwT, betp, kbp);
    if (ws_size >= need) {
        hv1_kernel<<<dim3(npx / 64, 4), 256, 0, stream>>>(x, rwT, hvp, npx);
        hv2_kernel<<<dim3(npx / 256, 16), 256, 0, stream>>>(hvp, betp, hv, npx);
    } else {
        hv_kernel<<<dim3(npx / 64), 256, 0, stream>>>(x, rwT, betp, hv);
    }
    invol_main<<<dim3(B * H_, 16), 256, 0, stream>>>(x, hv, kwb, kbp, out);
}

// Round 6
// 234.374 us; speedup vs baseline: 2.0082x; 2.0082x over previous
//
#include <hip/hip_runtime.h>

// Involution via bf16 MFMA tap-GEMM, operand-swapped (D[t][px]).
// R6: fix prep straggler — bias-sum moved from block 257's serial loop
// (t = tid&63 was loop-invariant -> one lane did 3136 dependent loads,
// ~300us tail) into the per-group u-row blocks as a wave shfl reduction.

#define C_    256
#define HID_  64
#define KS_   7
#define KK_   49
#define G_    256
#define H_    64
#define W_    64
#define HW_   4096
#define BN_EPS 1e-5f

typedef __attribute__((ext_vector_type(8))) short bf16x8;
typedef __attribute__((ext_vector_type(4))) float f32x4;

__device__ __forceinline__ ushort f2bf(float f) {
    unsigned u = __float_as_uint(f);
    return (ushort)((u + 0x7fffu + ((u >> 16) & 1u)) >> 16);   // RNE
}
__device__ __forceinline__ float bf2f(ushort s) {
    return __uint_as_float((unsigned)s << 16);
}

// ---------------------------------------------------------------- prep ----
// blocks 0..255:  kwb[g][t][k] bf16 (t<49 data, 51..63 zero; skip t=49,50)
// block 256:      rwT[k][o] = reduce_w[o][k]*bn_inv[o]; betp[o]
// block 257:      kbp[g][t] = bias (t<49), 0 (t in 50..63); t=49 owned below
// blocks 258+g:   kwb[g][49/50][k] = colsum(kw) hi/lo; kbp[g][49] = sum(kb)
__global__ __launch_bounds__(256) void prep_kernel(
    const float* __restrict__ kw, const float* __restrict__ kb,
    const float* __restrict__ reduce_w,
    const float* __restrict__ bn_gamma, const float* __restrict__ bn_beta,
    const float* __restrict__ bn_mean, const float* __restrict__ bn_var,
    ushort* __restrict__ kwb, float* __restrict__ rwT, float* __restrict__ betp,
    float* __restrict__ kbp)
{
    const int bid = blockIdx.x;
    if (bid < 256) {
        int idx  = bid * 256 + threadIdx.x;
        int base = idx * 16;
        int g    = base >> 12;
        int rem  = base & 4095;
        int t    = rem >> 6;
        int k0   = rem & 63;
        if (t == 49 || t == 50) return;      // owned by u-row blocks
        union { ushort s[16]; uint4 v[2]; } u;
        if (t < KK_) {
            const float* src = kw + ((size_t)(g * KK_ + t)) * HID_ + k0;
            #pragma unroll
            for (int i = 0; i < 16; ++i) u.s[i] = f2bf(src[i]);
        } else {
            #pragma unroll
            for (int i = 0; i < 16; ++i) u.s[i] = 0;
        }
        uint4* dst = (uint4*)(kwb + base);
        dst[0] = u.v[0];
        dst[1] = u.v[1];
    } else if (bid == 256) {
        int k = threadIdx.x;
        #pragma unroll 1
        for (int o = 0; o < HID_; ++o) {
            float inv = bn_gamma[o] * rsqrtf(bn_var[o] + BN_EPS);
            rwT[k * HID_ + o] = reduce_w[o * C_ + k] * inv;
        }
        if (k < HID_) {
            float inv = bn_gamma[k] * rsqrtf(bn_var[k] + BN_EPS);
            betp[k] = bn_beta[k] - bn_mean[k] * inv;
        }
    } else if (bid == 257) {
        for (int i = threadIdx.x; i < G_ * 64; i += 256) {
            int g = i >> 6, t = i & 63;
            if (t == 49) continue;           // written by u-row block
            kbp[i] = (t < KK_) ? kb[g * KK_ + t] : 0.f;
        }
    } else {
        const int g = bid - 258;
        __shared__ float part[4][64];
        const int k  = threadIdx.x & 63;
        const int pr = threadIdx.x >> 6;
        const int t0 = pr * 13;
        const int t1 = (t0 + 13 < KK_) ? t0 + 13 : KK_;
        float s = 0.f;
        for (int t = t0; t < t1; ++t)
            s += kw[((size_t)(g * KK_ + t)) * HID_ + k];
        part[pr][k] = s;
        __syncthreads();
        if (threadIdx.x < 64) {
            float u = part[0][k] + part[1][k] + part[2][k] + part[3][k];
            ushort uh = f2bf(u);
            ushort ul = f2bf(u - bf2f(uh));
            kwb[(size_t)g * 4096 + 49 * 64 + k] = uh;
            kwb[(size_t)g * 4096 + 50 * 64 + k] = ul;
            // bias-sum: wave-parallel reduce over the 49 taps
            float bs = (k < KK_) ? kb[g * KK_ + k] : 0.f;
            #pragma unroll
            for (int off = 32; off >= 1; off >>= 1) bs += __shfl_xor(bs, off);
            if (k == 0) kbp[g * 64 + 49] = bs;
        }
    }
}

// ----------------------------------------------------------------- hv1 ----
__global__ __launch_bounds__(256) void hv1_kernel(
    const float* __restrict__ x, const float* __restrict__ rwT,
    float* __restrict__ hvp, int npx)
{
    const int lane = threadIdx.x & 63;
    const int wq   = __builtin_amdgcn_readfirstlane(threadIdx.x >> 6);
    const int kq   = blockIdx.y;
    const int p    = blockIdx.x * 64 + lane;
    const int b    = p >> 12;
    const int hw   = p & 4095;

    float acc[16];
    #pragma unroll
    for (int j = 0; j < 16; ++j) acc[j] = 0.f;

    const float* xp = x + ((size_t)b * C_ + kq * 64) * HW_ + hw;
    const float* rw = rwT + (kq * 64) * HID_ + wq * 16;
    #pragma unroll 8
    for (int kk = 0; kk < 64; ++kk) {
        float xk = xp[(size_t)kk * HW_];
        #pragma unroll
        for (int j = 0; j < 16; ++j) acc[j] = fmaf(xk, rw[kk * HID_ + j], acc[j]);
    }
    float* dst = hvp + ((size_t)(kq * 64 + wq * 16)) * npx + p;
    #pragma unroll
    for (int j = 0; j < 16; ++j) dst[(size_t)j * npx] = acc[j];
}

// ----------------------------------------------------------------- hv2 ----
__global__ __launch_bounds__(256) void hv2_kernel(
    const float* __restrict__ hvp, const float* __restrict__ betp,
    ushort* __restrict__ hv, int npx)
{
    const int p  = blockIdx.x * 256 + threadIdx.x;
    const int o0 = blockIdx.y * 4;
    ushort s[4];
    #pragma unroll
    for (int j = 0; j < 4; ++j) {
        float v = 0.f;
        #pragma unroll
        for (int kq = 0; kq < 4; ++kq)
            v += hvp[(size_t)(kq * 64 + o0 + j) * npx + p];
        s[j] = f2bf(fmaxf(v + betp[o0 + j], 0.f));
    }
    uint2 w;
    w.x = (uint)s[0] | ((uint)s[1] << 16);
    w.y = (uint)s[2] | ((uint)s[3] << 16);
    *(uint2*)(hv + (size_t)p * HID_ + o0) = w;
}

// ---------------------------------------------------------------- main ----
__global__ __launch_bounds__(256) void invol_main(
    const float* __restrict__ x, const ushort* __restrict__ hv,
    const ushort* __restrict__ kwb, const float* __restrict__ kbp,
    float* __restrict__ out)
{
    __shared__ ushort hv_s[64 * HID_];         // 8 KB, XOR-swizzled rows
    __shared__ float  x_s[4][4][KS_][72];      // 32256 B: [wave][iter][row][col]

    const int tid  = threadIdx.x;
    const int lane = tid & 63;
    const int wave = __builtin_amdgcn_readfirstlane(tid >> 6);
    const int b  = blockIdx.x >> 6;
    const int y  = blockIdx.x & 63;
    const int gy = blockIdx.y;
    const int rowpix = (b << 12) + (y << 6);

    {   // stage hv row tile (swizzled: byte ^= (row&7)<<4)
        int px = tid >> 2, c = tid & 3;
        const uint4* src = (const uint4*)(hv + (size_t)(rowpix + px) * HID_ + c * 16);
        int d0 = (px * 128 + c * 32) ^ ((px & 7) << 4);
        int d1 = (px * 128 + c * 32 + 16) ^ ((px & 7) << 4);
        *(uint4*)((char*)hv_s + d0) = src[0];
        *(uint4*)((char*)hv_s + d1) = src[1];
    }

    // stage ALL 4 x-tiles for this wave's 4 groups (wave-private)
    const int  c0  = lane - 3;
    const int  c0c = c0 < 0 ? 0 : c0;
    const bool c0v = c0 >= 0;
    const int  c1  = 61 + lane;
    const int  c1c = c1 > 63 ? 63 : c1;
    const bool c1v = c1 <= 63;
    #pragma unroll
    for (int it = 0; it < 4; ++it) {
        const int g = gy * 16 + it * 4 + wave;
        const float* xg = x + ((size_t)(b * G_ + g)) * HW_;
        #pragma unroll
        for (int i = 0; i < KS_; ++i) {
            int yy = y + i - 3;
            bool rv = (unsigned)yy < (unsigned)H_;
            int yc = rv ? yy : 0;
            float v0 = xg[yc * W_ + c0c];
            x_s[wave][it][i][lane] = (rv && c0v) ? v0 : 0.f;
            if (lane < 6) {
                float v1 = xg[yc * W_ + c1c];
                x_s[wave][it][i][64 + lane] = (rv && c1v) ? v1 : 0.f;
            }
        }
    }
    __syncthreads();

    const int l15 = lane & 15;
    const int l4  = lane >> 4;

    // B frags (hv): loop-invariant across iters -> hoisted
    bf16x8 hb[2][4];
    #pragma unroll
    for (int ks = 0; ks < 2; ++ks)
        #pragma unroll
        for (int pn = 0; pn < 4; ++pn) {
            int row  = pn * 16 + l15;
            int byte = (row * 128 + ks * 64 + l4 * 16) ^ ((row & 7) << 4);
            hb[ks][pn] = *(const bf16x8*)((const char*)hv_s + byte);
        }

    // per-lane tap offsets into x_s row-space: t = tm*16 + l4*4 + r  (t<48)
    int offs[3][4];
    #pragma unroll
    for (int tm = 0; tm < 3; ++tm)
        #pragma unroll
        for (int r = 0; r < 4; ++r) {
            int t = tm * 16 + l4 * 4 + r;
            int i = (t * 147) >> 10;       // t/7 for t<64
            int j = t - i * 7;
            offs[tm][r] = i * 72 + j;
        }

    #pragma unroll
    for (int iter = 0; iter < 4; ++iter) {
        const int g = gy * 16 + iter * 4 + wave;

        // A frags (kw): rows t=tm*16+l15 (incl. u-rows 49,50)
        bf16x8 ka[2][4];
        const char* kwg = (const char*)kwb + (size_t)g * 8192;
        #pragma unroll
        for (int ks = 0; ks < 2; ++ks)
            #pragma unroll
            for (int tm = 0; tm < 4; ++tm) {
                int byte = (tm * 16 + l15) * 128 + ks * 64 + l4 * 16;
                ka[ks][tm] = *(const bf16x8*)(kwg + byte);
            }
        // bias rows for this lane (r dim): kbp[g][tm*16 + l4*4 .. +3]
        f32x4 kv[4];
        #pragma unroll
        for (int tm = 0; tm < 4; ++tm)
            kv[tm] = *(const f32x4*)(kbp + g * 64 + tm * 16 + l4 * 4);

        f32x4 acc[4][4];
        #pragma unroll
        for (int tm = 0; tm < 4; ++tm)
            #pragma unroll
            for (int pn = 0; pn < 4; ++pn) acc[tm][pn] = (f32x4)(0.f);
        #pragma unroll
        for (int ks = 0; ks < 2; ++ks)
            #pragma unroll
            for (int tm = 0; tm < 4; ++tm)
                #pragma unroll
                for (int pn = 0; pn < 4; ++pn)
                    acc[tm][pn] = __builtin_amdgcn_mfma_f32_16x16x32_bf16(
                        ka[ks][tm], hb[ks][pn], acc[tm][pn], 0, 0, 0);

        #pragma unroll
        for (int tm = 0; tm < 4; ++tm)
            #pragma unroll
            for (int pn = 0; pn < 4; ++pn)
                #pragma unroll
                for (int r = 0; r < 4; ++r) acc[tm][pn][r] += kv[tm][r];

        // norm: ssq over 49 taps; mean from u-rows (t=49 hi + t=50 lo + bsum)
        float m_all[4], inv_[4];
        #pragma unroll
        for (int pn = 0; pn < 4; ++pn) {
            float ssq = 0.f;
            #pragma unroll
            for (int tm = 0; tm < 3; ++tm)
                #pragma unroll
                for (int r = 0; r < 4; ++r) {
                    float e = acc[tm][pn][r];
                    ssq = fmaf(e, e, ssq);
                }
            float e48 = acc[3][pn][0];
            ssq += (l4 == 0) ? e48 * e48 : 0.f;
            ssq += __shfl_xor(ssq, 16);
            ssq += __shfl_xor(ssq, 32);
            // rows t=49 (r=1, has +bsum) and t=50 (r=2) live on l4==0 lanes
            float mr = acc[3][pn][1] + acc[3][pn][2];
            float m  = __shfl(mr, l15) * (1.f / 49.f);
            float ss = fmaxf(ssq - 49.f * m * m, 0.f);
            m_all[pn] = m;
            inv_[pn]  = 1.f / fmaxf(sqrtf(ss), 1e-6f);
        }

        // involution: out = (sum ker*x - mean*sum x) * inv
        float kx[4] = {0.f, 0.f, 0.f, 0.f};
        float xs[4] = {0.f, 0.f, 0.f, 0.f};
        const float* xw = &x_s[wave][iter][0][0];
        #pragma unroll
        for (int tm = 0; tm < 3; ++tm)
            #pragma unroll
            for (int r = 0; r < 4; ++r) {
                const float* base = xw + offs[tm][r] + l15;
                #pragma unroll
                for (int pn = 0; pn < 4; ++pn) {
                    float xv = base[pn * 16];
                    kx[pn] = fmaf(acc[tm][pn][r], xv, kx[pn]);
                    xs[pn] += xv;
                }
            }
        {   // t = 48 (i=6, j=6): valid only on l4==0 lanes
            const float* base = xw + 6 * 72 + 6 + l15;
            #pragma unroll
            for (int pn = 0; pn < 4; ++pn) {
                float xv = base[pn * 16];
                float kr = (l4 == 0) ? acc[3][pn][0] : 0.f;
                kx[pn] = fmaf(kr, xv, kx[pn]);
                xs[pn] += (l4 == 0) ? xv : 0.f;
            }
        }
        float ov[4];
        #pragma unroll
        for (int pn = 0; pn < 4; ++pn) {
            float k2 = kx[pn];
            k2 += __shfl_xor(k2, 16);
            k2 += __shfl_xor(k2, 32);
            float x2 = xs[pn];
            x2 += __shfl_xor(x2, 16);
            x2 += __shfl_xor(x2, 32);
            ov[pn] = (k2 - m_all[pn] * x2) * inv_[pn];
        }
        float outv = (l4 == 0) ? ov[0] : (l4 == 1) ? ov[1] : (l4 == 2) ? ov[2] : ov[3];
        out[((size_t)(b * G_ + g)) * HW_ + y * W_ + lane] = outv;
    }
}

// --------------------------------------------- tier-2 hv (single-stage) ----
__global__ __launch_bounds__(256) void hv_kernel(
    const float* __restrict__ x, const float* __restrict__ rwT,
    const float* __restrict__ betp, ushort* __restrict__ hv)
{
    const int lane = threadIdx.x & 63;
    const int q    = __builtin_amdgcn_readfirstlane(threadIdx.x >> 6);
    const int p    = blockIdx.x * 64 + lane;
    const int b    = p >> 12;
    const int hw   = p & 4095;
    float acc[16];
    #pragma unroll
    for (int j = 0; j < 16; ++j) acc[j] = betp[q * 16 + j];
    const float* xp = x + (size_t)b * C_ * HW_ + hw;
    #pragma unroll 8
    for (int k = 0; k < C_; ++k) {
        float xk = xp[(size_t)k * HW_];
        const float* rw = rwT + k * HID_ + q * 16;
        #pragma unroll
        for (int j = 0; j < 16; ++j) acc[j] = fmaf(xk, rw[j], acc[j]);
    }
    union { ushort s[16]; uint4 v[2]; } u;
    #pragma unroll
    for (int j = 0; j < 16; ++j) u.s[j] = f2bf(fmaxf(acc[j], 0.f));
    uint4* dst = (uint4*)(hv + (size_t)p * HID_ + q * 16);
    dst[0] = u.v[0];
    dst[1] = u.v[1];
}

// ---------------------------------------------------- fallback (no ws) ----
__global__ __launch_bounds__(256) void invol_fallback(
    const float* __restrict__ x, const float* __restrict__ reduce_w,
    const float* __restrict__ bn_gamma, const float* __restrict__ bn_beta,
    const float* __restrict__ bn_mean, const float* __restrict__ bn_var,
    const float* __restrict__ kw, const float* __restrict__ kb,
    float* __restrict__ out)
{
    __shared__ float rwT[C_][HID_ + 4];
    __shared__ float bns[HID_];
    __shared__ float bnb[HID_];
    const int tid = threadIdx.x;
    const int b  = blockIdx.z;
    const int g0 = blockIdx.y * 32;
    const int p  = blockIdx.x * 256 + tid;
    const int py = p >> 6;
    const int px = p & 63;
    #pragma unroll 1
    for (int o = 0; o < HID_; ++o) rwT[tid][o] = reduce_w[o * C_ + tid];
    if (tid < HID_) {
        float inv = bn_gamma[tid] * rsqrtf(bn_var[tid] + BN_EPS);
        bns[tid] = inv;
        bnb[tid] = bn_beta[tid] - bn_mean[tid] * inv;
    }
    __syncthreads();
    float hvv[HID_];
    #pragma unroll
    for (int o = 0; o < HID_; ++o) hvv[o] = 0.f;
    const float* xb = x + (size_t)b * C_ * HW_ + p;
    #pragma unroll 4
    for (int k = 0; k < C_; ++k) {
        float xk = xb[(size_t)k * HW_];
        const float4* wr = (const float4*)&rwT[k][0];
        #pragma unroll
        for (int o4 = 0; o4 < HID_ / 4; ++o4) {
            float4 w = wr[o4];
            hvv[o4*4+0] = fmaf(xk, w.x, hvv[o4*4+0]);
            hvv[o4*4+1] = fmaf(xk, w.y, hvv[o4*4+1]);
            hvv[o4*4+2] = fmaf(xk, w.z, hvv[o4*4+2]);
            hvv[o4*4+3] = fmaf(xk, w.w, hvv[o4*4+3]);
        }
    }
    #pragma unroll
    for (int o = 0; o < HID_; ++o) hvv[o] = fmaxf(fmaf(hvv[o], bns[o], bnb[o]), 0.f);
    #pragma unroll 1
    for (int gi = 0; gi < 32; ++gi) {
        const int g = g0 + gi;
        const float* kwg = kw + (size_t)g * KK_ * HID_;
        float acc[KK_];
        #pragma unroll
        for (int t = 0; t < KK_; ++t) {
            float a = kb[g * KK_ + t];
            const float4* row = (const float4*)(kwg + t * HID_);
            #pragma unroll
            for (int k4 = 0; k4 < HID_ / 4; ++k4) {
                float4 w = row[k4];
                a = fmaf(w.x, hvv[k4*4+0], a);
                a = fmaf(w.y, hvv[k4*4+1], a);
                a = fmaf(w.z, hvv[k4*4+2], a);
                a = fmaf(w.w, hvv[k4*4+3], a);
            }
            acc[t] = a;
        }
        float mean = 0.f;
        #pragma unroll
        for (int t = 0; t < KK_; ++t) mean += acc[t];
        mean *= (1.f / 49.f);
        float ss = 0.f;
        #pragma unroll
        for (int t = 0; t < KK_; ++t) { acc[t] -= mean; ss = fmaf(acc[t], acc[t], ss); }
        float inv = 1.f / fmaxf(sqrtf(ss), 1e-6f);
        const float* xg = x + ((size_t)(b * G_ + g)) * HW_;
        float oacc = 0.f;
        #pragma unroll
        for (int i = 0; i < KS_; ++i) {
            int yv = py + i - 3;
            bool rok = ((unsigned)yv < (unsigned)H_);
            const float* xrow = xg + yv * W_;
            #pragma unroll
            for (int j = 0; j < KS_; ++j) {
                int xx = px + j - 3;
                bool ok = rok && ((unsigned)xx < (unsigned)W_);
                float v = ok ? xrow[xx] : 0.f;
                oacc = fmaf(v, acc[i*7+j], oacc);
            }
        }
        out[((size_t)(b * G_ + g)) * HW_ + p] = oacc * inv;
    }
}

extern "C" void kernel_launch(void* const* d_in, const int* in_sizes, int n_in,
                              void* d_out, int out_size, void* d_ws, size_t ws_size,
                              hipStream_t stream) {
    const float* x        = (const float*)d_in[0];
    const float* reduce_w = (const float*)d_in[1];
    const float* bn_gamma = (const float*)d_in[2];
    const float* bn_beta  = (const float*)d_in[3];
    const float* bn_mean  = (const float*)d_in[4];
    const float* bn_var   = (const float*)d_in[5];
    const float* kproj_w  = (const float*)d_in[6];
    const float* kproj_b  = (const float*)d_in[7];
    float* out = (float*)d_out;
    const int B   = in_sizes[0] / (C_ * HW_);
    const int npx = B * HW_;

    size_t kwb_off = 0;
    size_t kwb_sz  = (size_t)G_ * 64 * 64 * 2;        // 2 MB
    size_t kbp_off = kwb_off + kwb_sz;
    size_t kbp_sz  = (size_t)G_ * 64 * 4;             // 64 KB
    size_t rwt_off = kbp_off + kbp_sz;
    size_t rwt_sz  = (size_t)C_ * HID_ * 4;           // 64 KB
    size_t bet_off = rwt_off + rwt_sz;
    size_t bet_sz  = 256;
    size_t hv_off  = bet_off + bet_sz;
    size_t hv_sz   = (size_t)npx * HID_ * 2;          // 2 MB
    size_t hvp_off = hv_off + hv_sz;
    size_t hvp_sz  = (size_t)4 * HID_ * npx * 4;      // 16 MB
    size_t need2   = hvp_off;                          // without hvp
    size_t need    = hvp_off + hvp_sz;

    if (ws_size < need2) {
        dim3 grid(HW_ / 256, G_ / 32, B);
        invol_fallback<<<grid, 256, 0, stream>>>(x, reduce_w, bn_gamma, bn_beta,
                                                 bn_mean, bn_var, kproj_w, kproj_b, out);
        return;
    }

    ushort* kwb  = (ushort*)((char*)d_ws + kwb_off);
    float*  kbp  = (float*)((char*)d_ws + kbp_off);
    float*  rwT  = (float*)((char*)d_ws + rwt_off);
    float*  betp = (float*)((char*)d_ws + bet_off);
    ushort* hv   = (ushort*)((char*)d_ws + hv_off);
    float*  hvp  = (float*)((char*)d_ws + hvp_off);

    prep_kernel<<<dim3(258 + G_), 256, 0, stream>>>(kproj_w, kproj_b, reduce_w,
                                                    bn_gamma, bn_beta, bn_mean, bn_var,
                                                    kwb, rwT, betp, kbp);
    if (ws_size >= need) {
        hv1_kernel<<<dim3(npx / 64, 4), 256, 0, stream>>>(x, rwT, hvp, npx);
        hv2_kernel<<<dim3(npx / 256, 16), 256, 0, stream>>>(hvp, betp, hv, npx);
    } else {
        hv_kernel<<<dim3(npx / 64), 256, 0, stream>>>(x, rwT, betp, hv);
    }
    invol_main<<<dim3(B * H_, 16), 256, 0, stream>>>(x, hv, kwb, kbp, out);
}